// Round 1
// baseline (133.799 us; speedup 1.0000x reference)
//
#include <hip/hip_runtime.h>

#define NB 8
#define NPTS 8192
#define TPB 256
#define UQ 4                      // query points per thread
#define TA (TPB * UQ)             // 1024 query points per block
#define ATILES (NPTS / TA)        // 8
#define NCHUNK 8                  // ref-dim split for parallelism
#define CSZ (NPTS / NCHUNK)       // 1024 ref points per chunk

// Pack ref points as (-2x, -2y, -2z, |r|^2) so the inner loop is 3 FMA + 1 MIN.
__global__ __launch_bounds__(TPB) void pack_kernel(const float* __restrict__ pts,
                                                   float4* __restrict__ packed) {
    int i = blockIdx.x * TPB + threadIdx.x;
    float x = pts[3 * i + 0];
    float y = pts[3 * i + 1];
    float z = pts[3 * i + 2];
    packed[i] = make_float4(-2.f * x, -2.f * y, -2.f * z, x * x + y * y + z * z);
}

// For each query point q: min over ref chunk of (-2 q.r + |r|^2); then
// dist = |q|^2 + min. Partial (per-chunk) mins merged with int atomicMin
// (valid: dist >= 0, positive float ordering == int ordering).
__global__ __launch_bounds__(TPB) void chamfer_min_kernel(
    const float* __restrict__ qpts,      // [NB][NPTS][3]
    const float4* __restrict__ rpk,      // [NB][NPTS] packed
    int* __restrict__ minarr)            // [NB*NPTS] float bits
{
    __shared__ float4 lds[CSZ];
    const int bid   = blockIdx.x;
    const int chunk = bid % NCHUNK;
    const int t2    = bid / NCHUNK;
    const int atile = t2 % ATILES;
    const int b     = t2 / ATILES;
    const int tid   = threadIdx.x;

    // stage ref chunk (coalesced float4)
    const float4* rsrc = rpk + b * NPTS + chunk * CSZ;
    for (int i = tid; i < CSZ; i += TPB) lds[i] = rsrc[i];

    const int qbase = b * NPTS + atile * TA + tid;
    float qx[UQ], qy[UQ], qz[UQ], q2[UQ], m[UQ];
#pragma unroll
    for (int u = 0; u < UQ; ++u) {
        int qi = qbase + u * TPB;
        qx[u] = qpts[3 * qi + 0];
        qy[u] = qpts[3 * qi + 1];
        qz[u] = qpts[3 * qi + 2];
        q2[u] = qx[u] * qx[u] + qy[u] * qy[u] + qz[u] * qz[u];
        m[u]  = 3.4e38f;
    }
    __syncthreads();

#pragma unroll 4
    for (int j = 0; j < CSZ; ++j) {
        const float4 r = lds[j];   // broadcast: all lanes same address, conflict-free
#pragma unroll
        for (int u = 0; u < UQ; ++u) {
            float v = fmaf(qx[u], r.x, fmaf(qy[u], r.y, fmaf(qz[u], r.z, r.w)));
            m[u] = fminf(m[u], v);
        }
    }

#pragma unroll
    for (int u = 0; u < UQ; ++u) {
        int qi = qbase + u * TPB;
        float d = fmaxf(q2[u] + m[u], 0.0f);
        atomicMin(&minarr[qi], __float_as_int(d));
    }
}

// Sum all 2*NB*NPTS mins, scaled by 1/(NB*NPTS); loss = mean(dist1)+mean(dist2).
__global__ __launch_bounds__(TPB) void reduce_kernel(const int* __restrict__ mins,
                                                     float* __restrict__ out) {
    int i = blockIdx.x * TPB + threadIdx.x;
    float v = __int_as_float(mins[i]) * (1.0f / (float)(NB * NPTS));
#pragma unroll
    for (int o = 32; o > 0; o >>= 1) v += __shfl_down(v, o);
    if ((threadIdx.x & 63) == 0) atomicAdd(out, v);
}

extern "C" void kernel_launch(void* const* d_in, const int* in_sizes, int n_in,
                              void* d_out, int out_size, void* d_ws, size_t ws_size,
                              hipStream_t stream) {
    const float* pred   = (const float*)d_in[0];   // [8,8192,3]
    const float* target = (const float*)d_in[1];   // [8,8192,3]
    float* out = (float*)d_out;

    char* ws = (char*)d_ws;
    int*    minarr = (int*)ws;                                   // 2*65536 ints (minT | minP)
    float4* pkP    = (float4*)(ws + (size_t)2 * NB * NPTS * 4);  // 1 MB
    float4* pkT    = pkP + (size_t)NB * NPTS;                    // 1 MB

    // init: mins to huge positive float (0x7F7F7F7F), accumulator (d_out) to 0
    hipMemsetAsync(minarr, 0x7F, (size_t)2 * NB * NPTS * 4, stream);
    hipMemsetAsync(out, 0, sizeof(float), stream);

    pack_kernel<<<NB * NPTS / TPB, TPB, 0, stream>>>(pred, pkP);
    pack_kernel<<<NB * NPTS / TPB, TPB, 0, stream>>>(target, pkT);

    const int nblk = NB * ATILES * NCHUNK;  // 512
    // dist1: for each target point, min over pred
    chamfer_min_kernel<<<nblk, TPB, 0, stream>>>(target, pkP, minarr);
    // dist2: for each pred point, min over target
    chamfer_min_kernel<<<nblk, TPB, 0, stream>>>(pred, pkT, minarr + NB * NPTS);

    reduce_kernel<<<2 * NB * NPTS / TPB, TPB, 0, stream>>>(minarr, out);
}

// Round 2
// 130.364 us; speedup vs baseline: 1.0263x; 1.0263x over previous
//
#include <hip/hip_runtime.h>
#include <hip/hip_bf16.h>

typedef short bf16x8 __attribute__((ext_vector_type(8)));
typedef float f32x16 __attribute__((ext_vector_type(16)));

#define NB 8
#define NPTS 8192
#define NSET (NB * NPTS)

static __device__ __forceinline__ short bfbits(float x) {
    __hip_bfloat16 h = __float2bfloat16(x);  // RNE
    return *reinterpret_cast<short*>(&h);
}
static __device__ __forceinline__ float bfval(float x) {
    __hip_bfloat16 h = __float2bfloat16(x);
    return __bfloat162float(h);
}

// Per point, emit K=16 bf16 row-features (A) and col-features (B) so that
// dot(A_t, B_p) = |t|^2 + |p|^2 - 2 t.p  (hi/lo bf16 split, err ~2^-16 rel).
__global__ __launch_bounds__(256) void pack_kernel(const float* __restrict__ pts,
                                                   short* __restrict__ A,
                                                   short* __restrict__ B) {
    int i = blockIdx.x * 256 + threadIdx.x;
    float x = pts[3 * i + 0], y = pts[3 * i + 1], z = pts[3 * i + 2];
    float n2 = x * x + y * y + z * z;

    float xh = bfval(x), yh = bfval(y), zh = bfval(z), nh = bfval(n2);
    short xhb = bfbits(x), yhb = bfbits(y), zhb = bfbits(z), nhb = bfbits(n2);
    short xlb = bfbits(x - xh), ylb = bfbits(y - yh), zlb = bfbits(z - zh), nlb = bfbits(n2 - nh);
    short one = bfbits(1.0f);
    short mxh = bfbits(-2.0f * xh), myh = bfbits(-2.0f * yh), mzh = bfbits(-2.0f * zh);
    short mxl = bfbits(-2.0f * __bfloat162float(*(__hip_bfloat16*)&xlb));
    short myl = bfbits(-2.0f * __bfloat162float(*(__hip_bfloat16*)&ylb));
    short mzl = bfbits(-2.0f * __bfloat162float(*(__hip_bfloat16*)&zlb));

    // A k=0..15: [1,1,t2h,t2l, xh,xh,xl, yh,yh,yl, zh,zh,zl, 0,0,0]
    bf16x8 a0, a1, b0, b1;
    a0[0] = one; a0[1] = one; a0[2] = nhb; a0[3] = nlb;
    a0[4] = xhb; a0[5] = xhb; a0[6] = xlb; a0[7] = yhb;
    a1[0] = yhb; a1[1] = ylb; a1[2] = zhb; a1[3] = zhb;
    a1[4] = zlb; a1[5] = 0;   a1[6] = 0;   a1[7] = 0;
    // B k=0..15: [p2h,p2l,1,1, -2xh,-2xl,-2xh, -2yh,-2yl,-2yh, -2zh,-2zl,-2zh, 0,0,0]
    b0[0] = nhb; b0[1] = nlb; b0[2] = one; b0[3] = one;
    b0[4] = mxh; b0[5] = mxl; b0[6] = mxh; b0[7] = myh;
    b1[0] = myl; b1[1] = myh; b1[2] = mzh; b1[3] = mzl;
    b1[4] = mzh; b1[5] = 0;   b1[6] = 0;   b1[7] = 0;

    *reinterpret_cast<bf16x8*>(&A[(size_t)i * 16])     = a0;
    *reinterpret_cast<bf16x8*>(&A[(size_t)i * 16 + 8]) = a1;
    *reinterpret_cast<bf16x8*>(&B[(size_t)i * 16])     = b0;
    *reinterpret_cast<bf16x8*>(&B[(size_t)i * 16 + 8]) = b1;
}

// One kernel, both chamfer directions. Each wave owns 64 rows (2 row-tiles of
// 32); streams 256 col-tiles; rowmins accumulate in registers; butterfly
// reduce + direct store (no atomics).
__global__ __launch_bounds__(256, 2) void chamfer_mfma_kernel(
    const short* __restrict__ targA, const short* __restrict__ targB,
    const short* __restrict__ predA, const short* __restrict__ predB,
    float* __restrict__ dist1, float* __restrict__ dist2)
{
    const int bid  = blockIdx.x;
    const int pass = bid >> 8;          // 0: rows=target, 1: rows=pred
    const int idx  = bid & 255;
    const int b    = idx >> 5;          // batch
    const int rg   = idx & 31;          // row group (256 rows)
    const int wave = threadIdx.x >> 6;
    const int lane = threadIdx.x & 63;
    const int l31  = lane & 31, h = lane >> 5;

    const short* Af = pass ? predA : targA;
    const short* Bf = pass ? targB : predB;
    float* out = pass ? dist2 : dist1;

    const int row0 = rg * 256 + wave * 64;

    const short* abase = Af + ((size_t)(b * NPTS + row0 + l31)) * 16 + h * 8;
    bf16x8 a0 = *reinterpret_cast<const bf16x8*>(abase);
    bf16x8 a1 = *reinterpret_cast<const bf16x8*>(abase + 32 * 16);

    const short* bbase = Bf + ((size_t)(b * NPTS + l31)) * 16 + h * 8;

    float acc0[16], acc1[16];
#pragma unroll
    for (int r = 0; r < 16; ++r) { acc0[r] = 3.4e38f; acc1[r] = 3.4e38f; }

    const f32x16 z = {0.f,0.f,0.f,0.f, 0.f,0.f,0.f,0.f, 0.f,0.f,0.f,0.f, 0.f,0.f,0.f,0.f};

    for (int cc = 0; cc < 256; cc += 32) {
        __syncthreads();  // keep the block's 4 waves converged for L1 reuse of B
#pragma unroll 2
        for (int ct = cc; ct < cc + 32; ct += 2) {
            bf16x8 bA = *reinterpret_cast<const bf16x8*>(bbase + (size_t)ct * 512);
            bf16x8 bB = *reinterpret_cast<const bf16x8*>(bbase + (size_t)(ct + 1) * 512);
            f32x16 cA0 = __builtin_amdgcn_mfma_f32_32x32x16_bf16(a0, bA, z, 0, 0, 0);
            f32x16 cB0 = __builtin_amdgcn_mfma_f32_32x32x16_bf16(a0, bB, z, 0, 0, 0);
            f32x16 cA1 = __builtin_amdgcn_mfma_f32_32x32x16_bf16(a1, bA, z, 0, 0, 0);
            f32x16 cB1 = __builtin_amdgcn_mfma_f32_32x32x16_bf16(a1, bB, z, 0, 0, 0);
#pragma unroll
            for (int r = 0; r < 16; ++r)
                acc0[r] = fminf(acc0[r], fminf(cA0[r], cB0[r]));
#pragma unroll
            for (int r = 0; r < 16; ++r)
                acc1[r] = fminf(acc1[r], fminf(cA1[r], cB1[r]));
        }
    }

    // reduce across the 32 lanes of each half (cols); rows live in (reg, h)
#pragma unroll
    for (int r = 0; r < 16; ++r) {
        float v0 = acc0[r], v1 = acc1[r];
#pragma unroll
        for (int s = 1; s < 32; s <<= 1) {
            v0 = fminf(v0, __shfl_xor(v0, s));
            v1 = fminf(v1, __shfl_xor(v1, s));
        }
        acc0[r] = v0; acc1[r] = v1;
    }

    if (l31 == 0) {
        float* ob = out + b * NPTS + row0;
#pragma unroll
        for (int r = 0; r < 16; ++r) {
            int rr = (r & 3) + 8 * (r >> 2) + 4 * h;  // verified C layout (m74/m101)
            ob[rr]      = acc0[r];
            ob[32 + rr] = acc1[r];
        }
    }
}

__global__ __launch_bounds__(256) void reduce_kernel(const float* __restrict__ mins,
                                                     float* __restrict__ out) {
    int i = blockIdx.x * 256 + threadIdx.x;
    float v = mins[i] * (1.0f / (float)NSET);
#pragma unroll
    for (int o = 32; o > 0; o >>= 1) v += __shfl_down(v, o);
    if ((threadIdx.x & 63) == 0) atomicAdd(out, v);
}

extern "C" void kernel_launch(void* const* d_in, const int* in_sizes, int n_in,
                              void* d_out, int out_size, void* d_ws, size_t ws_size,
                              hipStream_t stream) {
    const float* pred   = (const float*)d_in[0];   // [8,8192,3]
    const float* target = (const float*)d_in[1];   // [8,8192,3]
    float* out = (float*)d_out;

    char* ws = (char*)d_ws;
    float* dist1 = (float*)ws;                       // 65536 f32
    float* dist2 = dist1 + NSET;                     // 65536 f32
    short* tA = (short*)(ws + (size_t)2 * NSET * 4); // each 2 MB
    short* tB = tA + (size_t)NSET * 16;
    short* pA = tB + (size_t)NSET * 16;
    short* pB = pA + (size_t)NSET * 16;

    hipMemsetAsync(out, 0, sizeof(float), stream);

    pack_kernel<<<NSET / 256, 256, 0, stream>>>(target, tA, tB);
    pack_kernel<<<NSET / 256, 256, 0, stream>>>(pred, pA, pB);

    chamfer_mfma_kernel<<<512, 256, 0, stream>>>(tA, tB, pA, pB, dist1, dist2);

    reduce_kernel<<<2 * NSET / 256, 256, 0, stream>>>(dist1, out);
}

// Round 3
// 89.558 us; speedup vs baseline: 1.4940x; 1.4556x over previous
//
#include <hip/hip_runtime.h>
#include <hip/hip_bf16.h>

typedef short bf16x8 __attribute__((ext_vector_type(8)));
typedef float f32x16 __attribute__((ext_vector_type(16)));

#define NB 8
#define NPTS 8192
#define NSET (NB * NPTS)

static __device__ __forceinline__ short bfbits(float x) {
    __hip_bfloat16 h = __float2bfloat16(x);  // RNE
    return *reinterpret_cast<short*>(&h);
}
static __device__ __forceinline__ float bfval(float x) {
    __hip_bfloat16 h = __float2bfloat16(x);
    return __bfloat162float(h);
}

// Per point, emit K=16 bf16 row-features (A) and col-features (B) so that
// dot(A_t, B_p) = |t|^2 + |p|^2 - 2 t.p  (hi/lo bf16 split, err ~2^-16 rel).
// One launch packs both point sets.
__global__ __launch_bounds__(256) void pack2_kernel(
    const float* __restrict__ target, const float* __restrict__ pred,
    short* __restrict__ tA, short* __restrict__ tB,
    short* __restrict__ pA, short* __restrict__ pB) {
    int gi = blockIdx.x * 256 + threadIdx.x;
    int second = gi >= NSET;
    int i = second ? gi - NSET : gi;
    const float* pts = second ? pred : target;
    short* A = second ? pA : tA;
    short* B = second ? pB : tB;

    float x = pts[3 * i + 0], y = pts[3 * i + 1], z = pts[3 * i + 2];
    float n2 = x * x + y * y + z * z;

    float xh = bfval(x), yh = bfval(y), zh = bfval(z), nh = bfval(n2);
    short xhb = bfbits(x), yhb = bfbits(y), zhb = bfbits(z), nhb = bfbits(n2);
    short xlb = bfbits(x - xh), ylb = bfbits(y - yh), zlb = bfbits(z - zh), nlb = bfbits(n2 - nh);
    short one = bfbits(1.0f);
    short mxh = bfbits(-2.0f * xh), myh = bfbits(-2.0f * yh), mzh = bfbits(-2.0f * zh);
    short mxl = bfbits(-2.0f * __bfloat162float(*(__hip_bfloat16*)&xlb));
    short myl = bfbits(-2.0f * __bfloat162float(*(__hip_bfloat16*)&ylb));
    short mzl = bfbits(-2.0f * __bfloat162float(*(__hip_bfloat16*)&zlb));

    // A k=0..15: [1,1,n2h,n2l, xh,xh,xl, yh,yh,yl, zh,zh,zl, 0,0,0]
    bf16x8 a0, a1, b0, b1;
    a0[0] = one; a0[1] = one; a0[2] = nhb; a0[3] = nlb;
    a0[4] = xhb; a0[5] = xhb; a0[6] = xlb; a0[7] = yhb;
    a1[0] = yhb; a1[1] = ylb; a1[2] = zhb; a1[3] = zhb;
    a1[4] = zlb; a1[5] = 0;   a1[6] = 0;   a1[7] = 0;
    // B k=0..15: [n2h,n2l,1,1, -2xh,-2xl,-2xh, -2yh,-2yl,-2yh, -2zh,-2zl,-2zh, 0,0,0]
    b0[0] = nhb; b0[1] = nlb; b0[2] = one; b0[3] = one;
    b0[4] = mxh; b0[5] = mxl; b0[6] = mxh; b0[7] = myh;
    b1[0] = myl; b1[1] = myh; b1[2] = mzh; b1[3] = mzl;
    b1[4] = mzh; b1[5] = 0;   b1[6] = 0;   b1[7] = 0;

    *reinterpret_cast<bf16x8*>(&A[(size_t)i * 16])     = a0;
    *reinterpret_cast<bf16x8*>(&A[(size_t)i * 16 + 8]) = a1;
    *reinterpret_cast<bf16x8*>(&B[(size_t)i * 16])     = b0;
    *reinterpret_cast<bf16x8*>(&B[(size_t)i * 16 + 8]) = b1;
}

// Grid 1024: bit9 = direction, then 8 batches x 32 row-groups x 2 col-halves.
// Each wave: 2 row-frags (64 rows), 128 col-tiles in 64 pairs; min3-fold into
// 32 register row-min accumulators; butterfly + atomicMin epilogue.
__global__ __launch_bounds__(256, 4) void chamfer_mfma_kernel(
    const short* __restrict__ targA, const short* __restrict__ targB,
    const short* __restrict__ predA, const short* __restrict__ predB,
    int* __restrict__ dist1, int* __restrict__ dist2)
{
    const int bid  = blockIdx.x;
    const int pass = bid >> 9;
    const int r9   = bid & 511;
    const int b    = r9 >> 6;
    const int blk  = r9 & 63;
    const int rowgrp  = blk >> 1;
    const int colhalf = blk & 1;
    const int wave = threadIdx.x >> 6;
    const int lane = threadIdx.x & 63;
    const int l31  = lane & 31, h = lane >> 5;

    const short* Af = pass ? predA : targA;
    const short* Bf = pass ? targB : predB;
    int* out = pass ? dist2 : dist1;

    const int row0 = rowgrp * 256 + wave * 64;
    const short* abase = Af + ((size_t)(b * NPTS + row0 + l31)) * 16 + h * 8;
    bf16x8 a0 = *reinterpret_cast<const bf16x8*>(abase);
    bf16x8 a1 = *reinterpret_cast<const bf16x8*>(abase + 32 * 16);

    const short* bptr = Bf + ((size_t)(b * NPTS + colhalf * 4096 + l31)) * 16 + h * 8;

    float acc0[16], acc1[16];
#pragma unroll
    for (int r = 0; r < 16; ++r) { acc0[r] = 3.4e38f; acc1[r] = 3.4e38f; }

    const f32x16 z = {0.f,0.f,0.f,0.f, 0.f,0.f,0.f,0.f, 0.f,0.f,0.f,0.f, 0.f,0.f,0.f,0.f};

    bf16x8 bA = *reinterpret_cast<const bf16x8*>(bptr);
    bf16x8 bB = *reinterpret_cast<const bf16x8*>(bptr + 512);

    for (int it = 0; it < 64; ++it) {
        // prefetch next pair (clamped address on last iter; uniform branch-free)
        const short* pf = bptr + (it < 63 ? 1024 : 0);
        bf16x8 nA = *reinterpret_cast<const bf16x8*>(pf);
        bf16x8 nB = *reinterpret_cast<const bf16x8*>(pf + 512);

        f32x16 c0a = __builtin_amdgcn_mfma_f32_32x32x16_bf16(a0, bA, z, 0, 0, 0);
        f32x16 c0b = __builtin_amdgcn_mfma_f32_32x32x16_bf16(a0, bB, z, 0, 0, 0);
#pragma unroll
        for (int r = 0; r < 16; ++r)
            acc0[r] = fminf(acc0[r], fminf(c0a[r], c0b[r]));  // -> v_min3_f32

        f32x16 c1a = __builtin_amdgcn_mfma_f32_32x32x16_bf16(a1, bA, z, 0, 0, 0);
        f32x16 c1b = __builtin_amdgcn_mfma_f32_32x32x16_bf16(a1, bB, z, 0, 0, 0);
#pragma unroll
        for (int r = 0; r < 16; ++r)
            acc1[r] = fminf(acc1[r], fminf(c1a[r], c1b[r]));

        bA = nA; bB = nB;
        bptr += 1024;
    }

    // butterfly min over the 32 cols held in each half's lanes
#pragma unroll
    for (int r = 0; r < 16; ++r) {
        float v0 = acc0[r], v1 = acc1[r];
#pragma unroll
        for (int s = 1; s < 32; s <<= 1) {
            v0 = fminf(v0, __shfl_xor(v0, s));
            v1 = fminf(v1, __shfl_xor(v1, s));
        }
        acc0[r] = v0; acc1[r] = v1;
    }

    if (l31 == 0) {
        int* ob = out + b * NPTS + row0;
#pragma unroll
        for (int r = 0; r < 16; ++r) {
            int rr = (r & 3) + 8 * (r >> 2) + 4 * h;  // verified C layout (m74/m101)
            // clamp >=0 so positive-float bit order == int order for atomicMin
            atomicMin(&ob[rr],      __float_as_int(fmaxf(acc0[r], 0.0f)));
            atomicMin(&ob[32 + rr], __float_as_int(fmaxf(acc1[r], 0.0f)));
        }
    }
}

__global__ __launch_bounds__(256) void reduce_kernel(const int* __restrict__ mins,
                                                     float* __restrict__ out) {
    int i = blockIdx.x * 256 + threadIdx.x;
    float v = __int_as_float(mins[i]) * (1.0f / (float)NSET);
#pragma unroll
    for (int o = 32; o > 0; o >>= 1) v += __shfl_down(v, o);
    if ((threadIdx.x & 63) == 0) atomicAdd(out, v);
}

extern "C" void kernel_launch(void* const* d_in, const int* in_sizes, int n_in,
                              void* d_out, int out_size, void* d_ws, size_t ws_size,
                              hipStream_t stream) {
    const float* pred   = (const float*)d_in[0];   // [8,8192,3]
    const float* target = (const float*)d_in[1];   // [8,8192,3]
    float* out = (float*)d_out;

    char* ws = (char*)d_ws;
    int* dist1 = (int*)ws;                           // 65536 ints (float bits)
    int* dist2 = dist1 + NSET;                       // 65536 ints
    short* tA = (short*)(ws + (size_t)2 * NSET * 4); // each 2 MB
    short* tB = tA + (size_t)NSET * 16;
    short* pA = tB + (size_t)NSET * 16;
    short* pB = pA + (size_t)NSET * 16;

    hipMemsetAsync(dist1, 0x7F, (size_t)2 * NSET * 4, stream);  // +huge float
    hipMemsetAsync(out, 0, sizeof(float), stream);

    pack2_kernel<<<2 * NSET / 256, 256, 0, stream>>>(target, pred, tA, tB, pA, pB);

    chamfer_mfma_kernel<<<1024, 256, 0, stream>>>(tA, tB, pA, pB, dist1, dist2);

    reduce_kernel<<<2 * NSET / 256, 256, 0, stream>>>(dist1, out);
}